// Round 22
// baseline (226.045 us; speedup 1.0000x reference)
//
#include <hip/hip_runtime.h>
#include <hip/hip_bf16.h>

#define D_ 1024
#define F_ 4096
#define NH 16
#define HD 64
#define SEQ 2048
#define TOK 4096  // BATCH * SEQ

typedef short bf16x8 __attribute__((ext_vector_type(8)));
typedef float f32x4 __attribute__((ext_vector_type(4)));
typedef unsigned int u32x4 __attribute__((ext_vector_type(4)));

static __device__ __forceinline__ f32x4 mfma16(bf16x8 a, bf16x8 b, f32x4 c) {
  return __builtin_amdgcn_mfma_f32_16x16x32_bf16(a, b, c, 0, 0, 0);
}

// fp32 -> bf16 round-nearest-even (finite inputs)
static __device__ __forceinline__ unsigned short f2bf(float f) {
  union { float f; unsigned int u; } a; a.f = f;
  unsigned int u = a.u;
  u += 0x7fffu + ((u >> 16) & 1u);
  return (unsigned short)(u >> 16);
}

static __device__ __forceinline__ unsigned int cvtpk(float lo, float hi) {
  unsigned int r;
  asm("v_cvt_pk_bf16_f32 %0, %1, %2" : "=v"(r) : "v"(lo), "v"(hi));
  return r;
}

#define AS1 __attribute__((address_space(1)))
#define AS3 __attribute__((address_space(3)))
static __device__ __forceinline__ void gld16(const void* g, void* l) {
  __builtin_amdgcn_global_load_lds((const AS1 unsigned int*)(uintptr_t)(g),
                                   (AS3 unsigned int*)(uintptr_t)(l), 16, 0, 0);
}

#define WAITBAR0()                                       \
  do {                                                   \
    asm volatile("s_waitcnt vmcnt(0)" ::: "memory");     \
    __builtin_amdgcn_s_barrier();                        \
    __builtin_amdgcn_sched_barrier(0);                   \
  } while (0)

// ---------------- prep: merged weight transpose (vectorized writes) + LayerNorm1 --------------
__global__ __launch_bounds__(256) void prep_kernel(
    const float* __restrict__ wqkv, const float* __restrict__ wout,
    const float* __restrict__ wfc1, const float* __restrict__ wfc2,
    unsigned short* __restrict__ oqkv, unsigned short* __restrict__ oout,
    unsigned short* __restrict__ ofc1, unsigned short* __restrict__ ofc2,
    const float* __restrict__ x, const float* __restrict__ g,
    const float* __restrict__ bta, unsigned short* __restrict__ hout) {
  const int t = threadIdx.x;
  if (blockIdx.x < 12288) {
    __shared__ float tile[32][33];
    int idx = blockIdx.x;
    const float* in;
    unsigned short* out;
    int K, N;
    if (idx < 3072)      { in = wqkv; out = oqkv; K = 1024; N = 3072; }
    else if (idx < 4096) { in = wout; out = oout; K = 1024; N = 1024; idx -= 3072; }
    else if (idx < 8192) { in = wfc1; out = ofc1; K = 1024; N = 4096; idx -= 4096; }
    else                 { in = wfc2; out = ofc2; K = 4096; N = 1024; idx -= 8192; }
    int nt = N >> 5;
    int n0 = (idx % nt) * 32, k0 = (idx / nt) * 32;
    int tx = t & 31, ty = t >> 5;
#pragma unroll
    for (int i = 0; i < 32; i += 8)
      tile[ty + i][tx] = in[(size_t)(k0 + ty + i) * N + n0 + tx];
    __syncthreads();
    int n_loc = t >> 3, kq = (t & 7) * 4;
    unsigned short ob[4];
#pragma unroll
    for (int j = 0; j < 4; j++) ob[j] = f2bf(tile[kq + j][n_loc]);
    *(ushort4*)(out + (size_t)(n0 + n_loc) * K + k0 + kq) = *(ushort4*)ob;
  } else {
    int wv = t >> 6, lane = t & 63;
    int row = (blockIdx.x - 12288) * 4 + wv;
    const float4* xr = (const float4*)(x + (size_t)row * D_);
    float4 v[4];
    float s = 0.f, ss = 0.f;
#pragma unroll
    for (int i = 0; i < 4; i++) {
      v[i] = xr[i * 64 + lane];
      s += v[i].x + v[i].y + v[i].z + v[i].w;
      ss += v[i].x * v[i].x + v[i].y * v[i].y + v[i].z * v[i].z + v[i].w * v[i].w;
    }
#pragma unroll
    for (int off = 32; off >= 1; off >>= 1) {
      s += __shfl_xor(s, off);
      ss += __shfl_xor(ss, off);
    }
    float mu = s * (1.0f / D_);
    float var = ss * (1.0f / D_) - mu * mu;
    float r = rsqrtf(var + 1e-5f);
#pragma unroll
    for (int i = 0; i < 4; i++) {
      int col = i * 256 + lane * 4;
      unsigned short ob[4];
      ob[0] = f2bf((v[i].x - mu) * r * g[col + 0] + bta[col + 0]);
      ob[1] = f2bf((v[i].y - mu) * r * g[col + 1] + bta[col + 1]);
      ob[2] = f2bf((v[i].z - mu) * r * g[col + 2] + bta[col + 2]);
      ob[3] = f2bf((v[i].w - mu) * r * g[col + 3] + bta[col + 3]);
      *(ushort4*)(hout + (size_t)row * D_ + col) = *(ushort4*)ob;
    }
  }
}

// ---------------- LayerNorm: x [4096][1024] f32 -> out bf16, one wave per row ----------------
__global__ __launch_bounds__(256) void layernorm_bf16(const float* __restrict__ x,
                                                      const float* __restrict__ g,
                                                      const float* __restrict__ bta,
                                                      unsigned short* __restrict__ out) {
  int wv = threadIdx.x >> 6, lane = threadIdx.x & 63;
  int row = blockIdx.x * 4 + wv;
  const float4* xr = (const float4*)(x + (size_t)row * D_);
  float4 v[4];
  float s = 0.f, ss = 0.f;
#pragma unroll
  for (int i = 0; i < 4; i++) {
    v[i] = xr[i * 64 + lane];
    s += v[i].x + v[i].y + v[i].z + v[i].w;
    ss += v[i].x * v[i].x + v[i].y * v[i].y + v[i].z * v[i].z + v[i].w * v[i].w;
  }
#pragma unroll
  for (int off = 32; off >= 1; off >>= 1) {
    s += __shfl_xor(s, off);
    ss += __shfl_xor(ss, off);
  }
  float mu = s * (1.0f / D_);
  float var = ss * (1.0f / D_) - mu * mu;
  float r = rsqrtf(var + 1e-5f);
#pragma unroll
  for (int i = 0; i < 4; i++) {
    int col = i * 256 + lane * 4;
    unsigned short ob[4];
    ob[0] = f2bf((v[i].x - mu) * r * g[col + 0] + bta[col + 0]);
    ob[1] = f2bf((v[i].y - mu) * r * g[col + 1] + bta[col + 1]);
    ob[2] = f2bf((v[i].z - mu) * r * g[col + 2] + bta[col + 2]);
    ob[3] = f2bf((v[i].w - mu) * r * g[col + 3] + bta[col + 3]);
    *(ushort4*)(out + (size_t)row * D_ + col) = *(ushort4*)ob;
  }
}

// ---------------- GEMM v14: BK(32/64), NBUF pipeline, T2 swizzle, TN tile, XCD swz ------------
// BK=64: 2x MFMA/iter, HALF the barrier-iterations (fixed-overhead-bound kernels).
// TN=128+BK=64: 64KB LDS -> 2 blocks/CU; 32 MFMA/iter covers the vmcnt(0) wait.
// SWZ=1 (FC2): same-A grouping — each XCD gets contiguous m-panels (A hits its L2).
// MODE 0: QKV scatter; MODE 2: gelu bf16; MODE 5: f32 out = acc+bias+resid
template <int MODE, int NBUF, int TN, int SWZ, int BK>
__global__ __launch_bounds__(256,
    (BK == 64 ? (TN == 128 ? 2 : 3) : (NBUF == 2 ? 4 : 3))) void gemm_bt(
    const unsigned short* __restrict__ A, const unsigned short* __restrict__ Bt,
    const float* __restrict__ bias, const float* __restrict__ resid,
    void* __restrict__ outp, int M, int N, int K) {
  constexpr int ASZ = BK * 256;       // A bytes per buffer (128 rows x BK cols x 2B)
  constexpr int BSZ = TN * BK * 2;    // B bytes per buffer
  constexpr int NI = TN / 32;         // B fragments per wave (4 or 2)
  __shared__ __align__(16) char lds_all[NBUF * (ASZ + BSZ)];
  char* const a_lds = lds_all;
  char* const b_lds = lds_all + NBUF * ASZ;
  const int t = threadIdx.x;
  const int lane = t & 63, w = t >> 6;
  const int g = lane >> 4, lr = lane & 15;
  const int wm = (w >> 1) * 64, wn = (w & 1) * (TN / 2);
  int m0, n0;
  if constexpr (SWZ) {
    const int gx = gridDim.x;
    const int lid = blockIdx.y * gx + blockIdx.x;
    const int chunk = (gx * gridDim.y) >> 3;
    const int sidx = (lid & 7) * chunk + (lid >> 3);
    m0 = (sidx / gx) * 128;
    n0 = (sidx % gx) * TN;
  } else {
    m0 = blockIdx.y * 128;
    n0 = blockIdx.x * TN;
  }
  const int nIter = K / BK;

  const int mac0 = t >> 3;
  const int v0 = ((t & 7) ^ (mac0 & 7)) << 4;
  const int rsw = (lr & 7) << 4;
  const int rdA = lr * 128 + (((wm & 64) + g * 16) ^ rsw);
  const int rdB = lr * 128 + ((((TN == 128) ? (wn & 64) : ((wn & 32) * 2)) + g * 16) ^ rsw);

  f32x4 acc[4][NI] = {};

  if constexpr (BK == 32) {
    const int cc0 = v0 & 63;
    const int growA = mac0 + ((v0 >> 6) << 6);
    const int growB = mac0 + ((v0 >> 6) << (TN == 128 ? 6 : 5));
    const char* srcA0 = (const char*)A + ((size_t)(m0 + growA) * K) * 2 + cc0;
    const char* srcA1 = srcA0 + (size_t)32 * K * 2;
    const char* srcB0 = (const char*)Bt + ((size_t)(n0 + growB) * K) * 2 + cc0;
    const char* srcB1 = srcB0 + (size_t)32 * K * 2;  // used only when TN==128

#define STAGE32(IT, BUF)                                                  \
  do {                                                                    \
    size_t kb = (size_t)(IT) * 64;                                        \
    gld16(srcA0 + kb, a_lds + (BUF) * ASZ + t * 16);                      \
    gld16(srcA1 + kb, a_lds + (BUF) * ASZ + 4096 + t * 16);               \
    gld16(srcB0 + kb, b_lds + (BUF) * BSZ + t * 16);                      \
    if constexpr (TN == 128)                                              \
      gld16(srcB1 + kb, b_lds + (BUF) * BSZ + 4096 + t * 16);             \
  } while (0)

#define GSTEP32(BUF)                                                         \
  do {                                                                       \
    bf16x8 af[4], bfr[NI];                                                   \
    _Pragma("unroll") for (int mi = 0; mi < 4; mi++)                         \
        af[mi] = *(const bf16x8*)(a_lds + (BUF) * ASZ + rdA + mi * 2048);    \
    _Pragma("unroll") for (int ni = 0; ni < NI; ni++)                        \
        bfr[ni] = *(const bf16x8*)(b_lds + (BUF) * BSZ + rdB + ni * 2048);   \
    _Pragma("unroll") for (int mi = 0; mi < 4; mi++)                         \
        _Pragma("unroll") for (int ni = 0; ni < NI; ni++)                    \
            acc[mi][ni] = mfma16(af[mi], bfr[ni], acc[mi][ni]);              \
  } while (0)

    if constexpr (NBUF == 2) {
      STAGE32(0, 0);
      int cur = 0;
#pragma unroll 1
      for (int it = 0; it < nIter; ++it) {
        WAITBAR0();
        if (it + 1 < nIter) STAGE32(it + 1, cur ^ 1);
        GSTEP32(cur);
        cur ^= 1;
      }
    } else {
      STAGE32(0, 0);
      STAGE32(1, 1);
      int b0 = 0, b1 = 1, b2 = 2;
#pragma unroll 1
      for (int it = 0; it < nIter - 1; ++it) {
        if constexpr (TN == 128) {
          asm volatile("s_waitcnt vmcnt(4)" ::: "memory");
        } else {
          asm volatile("s_waitcnt vmcnt(3)" ::: "memory");
        }
        __builtin_amdgcn_s_barrier();
        __builtin_amdgcn_sched_barrier(0);
        if (it + 2 < nIter) STAGE32(it + 2, b2);
        GSTEP32(b0);
        int tmp = b0; b0 = b1; b1 = b2; b2 = tmp;
      }
      WAITBAR0();
      GSTEP32(b0);
    }
#undef STAGE32
#undef GSTEP32
  } else {
    // ---- BK == 64 (NBUF == 2): all rows are exact 128B macro-rows ----
    const char* sA0 = (const char*)A + ((size_t)(m0 + mac0) * K) * 2 + v0;
    const char* sA1 = sA0 + (size_t)32 * K * 2;
    const char* sA2 = sA0 + (size_t)64 * K * 2;
    const char* sA3 = sA0 + (size_t)96 * K * 2;
    const char* sB0 = (const char*)Bt + ((size_t)(n0 + mac0) * K) * 2 + v0;
    const char* sB1 = sB0 + (size_t)32 * K * 2;
    const char* sB2 = sB0 + (size_t)64 * K * 2;  // TN==128 only
    const char* sB3 = sB0 + (size_t)96 * K * 2;  // TN==128 only

#define STAGE64(IT, BUF)                                                  \
  do {                                                                    \
    size_t kb = (size_t)(IT) * 128;                                       \
    gld16(sA0 + kb, a_lds + (BUF) * ASZ + t * 16);                        \
    gld16(sA1 + kb, a_lds + (BUF) * ASZ + 4096 + t * 16);                 \
    gld16(sA2 + kb, a_lds + (BUF) * ASZ + 8192 + t * 16);                 \
    gld16(sA3 + kb, a_lds + (BUF) * ASZ + 12288 + t * 16);                \
    gld16(sB0 + kb, b_lds + (BUF) * BSZ + t * 16);                        \
    gld16(sB1 + kb, b_lds + (BUF) * BSZ + 4096 + t * 16);                 \
    if constexpr (TN == 128) {                                            \
      gld16(sB2 + kb, b_lds + (BUF) * BSZ + 8192 + t * 16);               \
      gld16(sB3 + kb, b_lds + (BUF) * BSZ + 12288 + t * 16);              \
    }                                                                     \
  } while (0)

#define GSTEP64(BUF)                                                           \
  do {                                                                         \
    _Pragma("unroll") for (int kk = 0; kk < 2; ++kk) {                         \
      bf16x8 af[4], bfr[NI];                                                   \
      _Pragma("unroll") for (int mi = 0; mi < 4; mi++)                         \
          af[mi] = *(const bf16x8*)(a_lds + (BUF) * ASZ +                      \
                                    (wm + mi * 16 + lr) * 128 +                \
                                    ((kk * 64 + g * 16) ^ rsw));               \
      _Pragma("unroll") for (int ni = 0; ni < NI; ni++)                        \
          bfr[ni] = *(const bf16x8*)(b_lds + (BUF) * BSZ +                     \
                                     (wn + ni * 16 + lr) * 128 +               \
                                     ((kk * 64 + g * 16) ^ rsw));              \
      _Pragma("unroll") for (int mi = 0; mi < 4; mi++)                         \
          _Pragma("unroll") for (int ni = 0; ni < NI; ni++)                    \
              acc[mi][ni] = mfma16(af[mi], bfr[ni], acc[mi][ni]);              \
    }                                                                          \
  } while (0)

    STAGE64(0, 0);
    int cur = 0;
#pragma unroll 1
    for (int it = 0; it < nIter; ++it) {
      WAITBAR0();
      if (it + 1 < nIter) STAGE64(it + 1, cur ^ 1);
      GSTEP64(cur);
      cur ^= 1;
    }
#undef STAGE64
#undef GSTEP64
  }

  if (MODE == 0) {
    const int whichB = n0 >> 10;  // block-uniform (1024 % 128 == 0)
    if (whichB == 2) {
      // ---- V epilogue: LDS transpose + sigma permute, then coalesced 16B writes ----
      __syncthreads();  // all waves done reading pipeline LDS
#pragma unroll
      for (int mi = 0; mi < 4; mi++) {
        int colbase = wm + mi * 16 + g * 4;  // nn_local base (multiple of 4)
        int off = colbase & 63;
        int cpos = (off & 35) | ((off & 4) << 1) | ((off & 8) << 1) | ((off & 16) >> 2);
        int nplb = ((colbase & 64) + cpos) * 2;  // byte base within 256B row
#pragma unroll
        for (int ni = 0; ni < NI; ni++) {
          int rl = wn + ni * 16 + lr;  // dd_local row
          float bia = bias[n0 + rl];
          unsigned short v4[4];
#pragma unroll
          for (int j = 0; j < 4; j++) v4[j] = f2bf(acc[mi][ni][j] + bia);
          int byt = rl * 256 + (nplb ^ ((rl & 7) << 4));
          *(unsigned long long*)(lds_all + byt) = *(const unsigned long long*)v4;
        }
      }
      __syncthreads();
      int r = t >> 1, half = t & 1;
      int hh = ((n0 & 1023) >> 6) + (r >> 6);
      int dd = r & 63;
      int bb = m0 >> 11;
      char* dst = (char*)outp +
                  2 * ((size_t)2 * TOK * D_ +
                       ((size_t)(bb * NH + hh) * HD + dd) * SEQ + (m0 & 2047) + half * 64);
#pragma unroll
      for (int c = 0; c < 8; c++) {
        int src = r * 256 + ((half * 128 + c * 16) ^ ((r & 7) << 4));
        *(int4*)(dst + c * 16) = *(const int4*)(lds_all + src);
      }
    } else {
      // ---- q/k epilogue: direct stores (32B-coalesced per quarter-wave) ----
#pragma unroll
      for (int mi = 0; mi < 4; mi++) {
#pragma unroll
        for (int ni = 0; ni < NI; ni++) {
#pragma unroll
          for (int j = 0; j < 4; j++) {
            int row = m0 + wm + mi * 16 + g * 4 + j;
            int col = n0 + wn + ni * 16 + lr;
            float val = acc[mi][ni][j] + bias[col];
            int cc = col & 1023;
            int hh = cc >> 6, dd = cc & 63;
            int bb = row >> 11, nn = row & 2047;
            if (whichB == 0) val *= 0.18033688011112042f;  // 0.125 * log2(e)
            ((unsigned short*)outp)[(size_t)whichB * (TOK * D_) +
                                    (((size_t)(bb * NH + hh) * SEQ + nn) << 6) + dd] =
                f2bf(val);
          }
        }
      }
    }
    return;
  }

#pragma unroll
  for (int mi = 0; mi < 4; mi++) {
#pragma unroll
    for (int ni = 0; ni < NI; ni++) {
#pragma unroll
      for (int j = 0; j < 4; j++) {
        int row = m0 + wm + mi * 16 + g * 4 + j;
        int col = n0 + wn + ni * 16 + lr;
        float val = acc[mi][ni][j];
        if (MODE == 2) {
          val += bias[col];
          val = 0.5f * val * (1.0f + erff(val * 0.70710678118f));
          ((unsigned short*)outp)[(size_t)row * N + col] = f2bf(val);
        } else if (MODE == 5) {
          val += bias[col] + resid[(size_t)row * N + col];
          ((float*)outp)[(size_t)row * N + col] = val;
        }
      }
    }
  }
}

// ---------------- Flash attention v10 (r12 body, proven 62us): no max tracking ----------------
// q (pre-scaled by 0.125*log2e), k: [B][H][N][64]; vT: [B][H][64][N] (sigma-permuted).
// 1024 blocks x 4 waves; 64 q-rows/block (16/wave); KVBLK=64 2-buffer.
__global__ __launch_bounds__(256, 4) void attn_kernel(const unsigned short* __restrict__ q,
                                                      const unsigned short* __restrict__ k,
                                                      const unsigned short* __restrict__ vT,
                                                      unsigned short* __restrict__ ao) {
  // LDS arena: K buf0 @0, K buf1 @8192, V buf0 @16384, V buf1 @24576
  __shared__ __align__(16) char ldsb[32768];
  const int t = threadIdx.x, lane = t & 63, w = t >> 6;
  const int g = lane >> 4, lr = lane & 15;
  const int bid = (blockIdx.x & 7) * 128 + (blockIdx.x >> 3);  // XCD swizzle
  const int qt = bid & 31, bh = bid >> 5;
  const int bb = bh >> 4, hh = bh & 15;

  const unsigned short* qp = q + ((size_t)bh * SEQ + qt * 64 + w * 16) * HD;
  bf16x8 qf0 = *(const bf16x8*)(qp + lr * HD + g * 8);
  bf16x8 qf1 = *(const bf16x8*)(qp + lr * HD + 32 + g * 8);

  f32x4 oacc[4] = {};
  f32x4 spv = {0.f, 0.f, 0.f, 0.f};  // 4 parallel denominator chains

  const int srow = t >> 3, sc = (t & 7) << 4;
  const int ssw = sc ^ ((srow & 7) << 4);
  const char* kgl = (const char*)(k + (size_t)bh * SEQ * HD) + srow * 128 + ssw;
  const char* vgl = (const char*)(vT + (size_t)bh * HD * SEQ) + (size_t)srow * 4096 + ssw;
  char* kdst = ldsb + w * 1024;            // + buf*8192 (+4096 for rows 32-63)
  char* vdst = ldsb + 16384 + w * 1024;    // + buf*8192

  const int rsw = (lr & 7) << 4;
  const char* r0 = ldsb + lr * 128 + ((g * 16) ^ rsw);
  const char* r1 = ldsb + lr * 128 + ((64 + g * 16) ^ rsw);

#define ISSUE(BUF)                                   \
  do {                                               \
    gld16(kgl, kdst + (BUF) * 8192);                 \
    gld16(kgl + 4096, kdst + (BUF) * 8192 + 4096);   \
    gld16(vgl, vdst + (BUF) * 8192);                 \
    gld16(vgl + 131072, vdst + (BUF) * 8192 + 4096); \
    kgl += 8192;                                     \
    vgl += 128;                                      \
  } while (0)

#define COMPUTE(BUF)                                                                     \
  do {                                                                                   \
    f32x4 sT[4];                                                                         \
    __builtin_amdgcn_s_setprio(1);                                                       \
    _Pragma("unroll") for (int sb = 0; sb < 4; ++sb) {                                   \
      bf16x8 kf0 = *(const bf16x8*)(r0 + (BUF) * 8192 + sb * 2048);                      \
      bf16x8 kf1 = *(const bf16x8*)(r1 + (BUF) * 8192 + sb * 2048);                      \
      f32x4 zz = {};                                                                     \
      zz = mfma16(kf0, qf0, zz);                                                         \
      sT[sb] = mfma16(kf1, qf1, zz);                                                     \
    }                                                                                    \
    __builtin_amdgcn_s_setprio(0);                                                       \
    float p[4][4];                                                                       \
    _Pragma("unroll") for (int sb = 0; sb < 4; ++sb) _Pragma("unroll")                   \
        for (int jr = 0; jr < 4; ++jr) {                                                 \
      p[sb][jr] = exp2f(sT[sb][jr]);                                                     \
      spv[jr] += p[sb][jr];                                                              \
    }                                                                                    \
    u32x4 pA[2];                                                                         \
    _Pragma("unroll") for (int kk = 0; kk < 2; ++kk) pA[kk] =                            \
        (u32x4){cvtpk(p[2 * kk][0], p[2 * kk][1]), cvtpk(p[2 * kk][2], p[2 * kk][3]),    \
                cvtpk(p[2 * kk + 1][0], p[2 * kk + 1][1]),                               \
                cvtpk(p[2 * kk + 1][2], p[2 * kk + 1][3])};                              \
    __builtin_amdgcn_s_setprio(1);                                                       \
    _Pragma("unroll") for (int vb = 0; vb < 4; ++vb) {                                   \
      bf16x8 v0 = *(const bf16x8*)(r0 + 16384 + (BUF) * 8192 + vb * 2048);               \
      bf16x8 v1 = *(const bf16x8*)(r1 + 16384 + (BUF) * 8192 + vb * 2048);               \
      oacc[vb] = mfma16(__builtin_bit_cast(bf16x8, pA[0]), v0, oacc[vb]);                \
      oacc[vb] = mfma16(__builtin_bit_cast(bf16x8, pA[1]), v1, oacc[vb]);                \
    }                                                                                    \
    __builtin_amdgcn_s_setprio(0);                                                       \
  } while (0)

  ISSUE(0);  // prolog: tile 0 loads in flight

  int staged = 1;
#pragma unroll 1
  for (int i2 = 0; i2 < SEQ / 128; ++i2) {
    WAITBAR0();
    if (staged < SEQ / 64) { ISSUE(1); ++staged; }
    COMPUTE(0);
    WAITBAR0();
    if (staged < SEQ / 64) { ISSUE(0); ++staged; }
    COMPUTE(1);
  }
#undef ISSUE
#undef COMPUTE

  float sp = (spv[0] + spv[1]) + (spv[2] + spv[3]);
  sp += __shfl_xor(sp, 16);
  sp += __shfl_xor(sp, 32);

#pragma unroll
  for (int jj = 0; jj < 4; ++jj) {
    float li = 1.0f / __shfl(sp, g * 4 + jj);
    int nrow = qt * 64 + w * 16 + g * 4 + jj;
#pragma unroll
    for (int vb = 0; vb < 4; ++vb)
      ao[((size_t)bb * SEQ + nrow) * D_ + hh * HD + vb * 16 + lr] = f2bf(oacc[vb][jj] * li);
  }
}

extern "C" void kernel_launch(void* const* d_in, const int* in_sizes, int n_in,
                              void* d_out, int out_size, void* d_ws, size_t ws_size,
                              hipStream_t stream) {
  const float* x     = (const float*)d_in[0];
  const float* w_qkv = (const float*)d_in[1];
  const float* b_qkv = (const float*)d_in[2];
  const float* w_out = (const float*)d_in[3];
  const float* b_out = (const float*)d_in[4];
  const float* w_fc1 = (const float*)d_in[5];
  const float* b_fc1 = (const float*)d_in[6];
  const float* w_fc2 = (const float*)d_in[7];
  const float* b_fc2 = (const float*)d_in[8];
  const float* ln1_g = (const float*)d_in[9];
  const float* ln1_b = (const float*)d_in[10];
  const float* ln2_g = (const float*)d_in[11];
  const float* ln2_b = (const float*)d_in[12];
  float* out = (float*)d_out;

  char* ws = (char*)d_ws;
  unsigned short* wqkvT = (unsigned short*)(ws);              //  6 MB [3072][1024]
  unsigned short* woutT = (unsigned short*)(ws + 6291456);    //  2 MB [1024][1024]
  unsigned short* wfc1T = (unsigned short*)(ws + 8388608);    //  8 MB [4096][1024]
  unsigned short* wfc2T = (unsigned short*)(ws + 16777216);   //  8 MB [1024][4096]
  unsigned short* h     = (unsigned short*)(ws + 25165824);   //  8 MB [4096][1024]
  unsigned short* qkv   = (unsigned short*)(ws + 33554432);   // 24 MB q,k,vT
  unsigned short* ao    = (unsigned short*)(ws + 58720256);   //  8 MB [4096][1024]
  float*          x1    = (float*)(ws + 67108864);            // 16 MB [4096][1024]
  unsigned short* hg    = (unsigned short*)(ws + 83886080);   // 32 MB [4096][4096]

  prep_kernel<<<13312, 256, 0, stream>>>(w_qkv, w_out, w_fc1, w_fc2,
                                         wqkvT, woutT, wfc1T, wfc2T,
                                         x, ln1_g, ln1_b, h);
  gemm_bt<0, 2, 128, 0, 64><<<dim3(24, 32), 256, 0, stream>>>(h, wqkvT, b_qkv, nullptr, qkv,
                                                              TOK, 3072, 1024);
  attn_kernel<<<1024, 256, 0, stream>>>(qkv, qkv + (size_t)TOK * D_, qkv + 2 * (size_t)TOK * D_,
                                        ao);
  gemm_bt<5, 2, 64, 0, 64><<<dim3(16, 32), 256, 0, stream>>>(ao, woutT, b_out, x, x1,
                                                             TOK, 1024, 1024);
  layernorm_bf16<<<TOK / 4, 256, 0, stream>>>(x1, ln2_g, ln2_b, h);
  gemm_bt<2, 2, 128, 0, 64><<<dim3(32, 32), 256, 0, stream>>>(h, wfc1T, b_fc1, nullptr, hg,
                                                              TOK, 4096, 1024);
  gemm_bt<5, 2, 64, 1, 64><<<dim3(16, 32), 256, 0, stream>>>(hg, wfc2T, b_fc2, x1, out,
                                                             TOK, 1024, 4096);
}

// Round 23
// 223.131 us; speedup vs baseline: 1.0131x; 1.0131x over previous
//
#include <hip/hip_runtime.h>
#include <hip/hip_bf16.h>

#define D_ 1024
#define F_ 4096
#define NH 16
#define HD 64
#define SEQ 2048
#define TOK 4096  // BATCH * SEQ

typedef short bf16x8 __attribute__((ext_vector_type(8)));
typedef float f32x4 __attribute__((ext_vector_type(4)));
typedef unsigned int u32x4 __attribute__((ext_vector_type(4)));

static __device__ __forceinline__ f32x4 mfma16(bf16x8 a, bf16x8 b, f32x4 c) {
  return __builtin_amdgcn_mfma_f32_16x16x32_bf16(a, b, c, 0, 0, 0);
}

// fp32 -> bf16 round-nearest-even (finite inputs)
static __device__ __forceinline__ unsigned short f2bf(float f) {
  union { float f; unsigned int u; } a; a.f = f;
  unsigned int u = a.u;
  u += 0x7fffu + ((u >> 16) & 1u);
  return (unsigned short)(u >> 16);
}

static __device__ __forceinline__ unsigned int cvtpk(float lo, float hi) {
  unsigned int r;
  asm("v_cvt_pk_bf16_f32 %0, %1, %2" : "=v"(r) : "v"(lo), "v"(hi));
  return r;
}

#define AS1 __attribute__((address_space(1)))
#define AS3 __attribute__((address_space(3)))
static __device__ __forceinline__ void gld16(const void* g, void* l) {
  __builtin_amdgcn_global_load_lds((const AS1 unsigned int*)(uintptr_t)(g),
                                   (AS3 unsigned int*)(uintptr_t)(l), 16, 0, 0);
}

#define WAITBAR0()                                       \
  do {                                                   \
    asm volatile("s_waitcnt vmcnt(0)" ::: "memory");     \
    __builtin_amdgcn_s_barrier();                        \
    __builtin_amdgcn_sched_barrier(0);                   \
  } while (0)

// ---------------- prep: merged weight transpose (vectorized writes) + LayerNorm1 --------------
__global__ __launch_bounds__(256) void prep_kernel(
    const float* __restrict__ wqkv, const float* __restrict__ wout,
    const float* __restrict__ wfc1, const float* __restrict__ wfc2,
    unsigned short* __restrict__ oqkv, unsigned short* __restrict__ oout,
    unsigned short* __restrict__ ofc1, unsigned short* __restrict__ ofc2,
    const float* __restrict__ x, const float* __restrict__ g,
    const float* __restrict__ bta, unsigned short* __restrict__ hout) {
  const int t = threadIdx.x;
  if (blockIdx.x < 12288) {
    __shared__ float tile[32][33];
    int idx = blockIdx.x;
    const float* in;
    unsigned short* out;
    int K, N;
    if (idx < 3072)      { in = wqkv; out = oqkv; K = 1024; N = 3072; }
    else if (idx < 4096) { in = wout; out = oout; K = 1024; N = 1024; idx -= 3072; }
    else if (idx < 8192) { in = wfc1; out = ofc1; K = 1024; N = 4096; idx -= 4096; }
    else                 { in = wfc2; out = ofc2; K = 4096; N = 1024; idx -= 8192; }
    int nt = N >> 5;
    int n0 = (idx % nt) * 32, k0 = (idx / nt) * 32;
    int tx = t & 31, ty = t >> 5;
#pragma unroll
    for (int i = 0; i < 32; i += 8)
      tile[ty + i][tx] = in[(size_t)(k0 + ty + i) * N + n0 + tx];
    __syncthreads();
    int n_loc = t >> 3, kq = (t & 7) * 4;
    unsigned short ob[4];
#pragma unroll
    for (int j = 0; j < 4; j++) ob[j] = f2bf(tile[kq + j][n_loc]);
    *(ushort4*)(out + (size_t)(n0 + n_loc) * K + k0 + kq) = *(ushort4*)ob;
  } else {
    int wv = t >> 6, lane = t & 63;
    int row = (blockIdx.x - 12288) * 4 + wv;
    const float4* xr = (const float4*)(x + (size_t)row * D_);
    float4 v[4];
    float s = 0.f, ss = 0.f;
#pragma unroll
    for (int i = 0; i < 4; i++) {
      v[i] = xr[i * 64 + lane];
      s += v[i].x + v[i].y + v[i].z + v[i].w;
      ss += v[i].x * v[i].x + v[i].y * v[i].y + v[i].z * v[i].z + v[i].w * v[i].w;
    }
#pragma unroll
    for (int off = 32; off >= 1; off >>= 1) {
      s += __shfl_xor(s, off);
      ss += __shfl_xor(ss, off);
    }
    float mu = s * (1.0f / D_);
    float var = ss * (1.0f / D_) - mu * mu;
    float r = rsqrtf(var + 1e-5f);
#pragma unroll
    for (int i = 0; i < 4; i++) {
      int col = i * 256 + lane * 4;
      unsigned short ob[4];
      ob[0] = f2bf((v[i].x - mu) * r * g[col + 0] + bta[col + 0]);
      ob[1] = f2bf((v[i].y - mu) * r * g[col + 1] + bta[col + 1]);
      ob[2] = f2bf((v[i].z - mu) * r * g[col + 2] + bta[col + 2]);
      ob[3] = f2bf((v[i].w - mu) * r * g[col + 3] + bta[col + 3]);
      *(ushort4*)(hout + (size_t)row * D_ + col) = *(ushort4*)ob;
    }
  }
}

// ---------------- LayerNorm: x [4096][1024] f32 -> out bf16, one wave per row ----------------
__global__ __launch_bounds__(256) void layernorm_bf16(const float* __restrict__ x,
                                                      const float* __restrict__ g,
                                                      const float* __restrict__ bta,
                                                      unsigned short* __restrict__ out) {
  int wv = threadIdx.x >> 6, lane = threadIdx.x & 63;
  int row = blockIdx.x * 4 + wv;
  const float4* xr = (const float4*)(x + (size_t)row * D_);
  float4 v[4];
  float s = 0.f, ss = 0.f;
#pragma unroll
  for (int i = 0; i < 4; i++) {
    v[i] = xr[i * 64 + lane];
    s += v[i].x + v[i].y + v[i].z + v[i].w;
    ss += v[i].x * v[i].x + v[i].y * v[i].y + v[i].z * v[i].z + v[i].w * v[i].w;
  }
#pragma unroll
  for (int off = 32; off >= 1; off >>= 1) {
    s += __shfl_xor(s, off);
    ss += __shfl_xor(ss, off);
  }
  float mu = s * (1.0f / D_);
  float var = ss * (1.0f / D_) - mu * mu;
  float r = rsqrtf(var + 1e-5f);
#pragma unroll
  for (int i = 0; i < 4; i++) {
    int col = i * 256 + lane * 4;
    unsigned short ob[4];
    ob[0] = f2bf((v[i].x - mu) * r * g[col + 0] + bta[col + 0]);
    ob[1] = f2bf((v[i].y - mu) * r * g[col + 1] + bta[col + 1]);
    ob[2] = f2bf((v[i].z - mu) * r * g[col + 2] + bta[col + 2]);
    ob[3] = f2bf((v[i].w - mu) * r * g[col + 3] + bta[col + 3]);
    *(ushort4*)(out + (size_t)row * D_ + col) = *(ushort4*)ob;
  }
}

// ---------------- GEMM v13 (r21 best): BK(32/64), NBUF pipeline, T2 swizzle, XCD swz ----------
// BK=64 (TN=64): 16 MFMA/iter, HALF the barrier-iterations (fixed-overhead bound FC2/OP).
// SWZ=1 (FC2): same-A grouping — each XCD gets contiguous m-panels (A hits its L2).
// MODE 0: QKV scatter; MODE 2: gelu bf16; MODE 5: f32 out = acc+bias+resid
template <int MODE, int NBUF, int TN, int SWZ, int BK>
__global__ __launch_bounds__(256, (BK == 64 ? 3 : (NBUF == 2 ? 4 : 3))) void gemm_bt(
    const unsigned short* __restrict__ A, const unsigned short* __restrict__ Bt,
    const float* __restrict__ bias, const float* __restrict__ resid,
    void* __restrict__ outp, int M, int N, int K) {
  constexpr int ASZ = BK * 256;       // A bytes per buffer (128 rows x BK cols x 2B)
  constexpr int BSZ = TN * BK * 2;    // B bytes per buffer
  constexpr int NI = TN / 32;         // B fragments per wave (4 or 2)
  __shared__ __align__(16) char lds_all[NBUF * (ASZ + BSZ)];
  char* const a_lds = lds_all;
  char* const b_lds = lds_all + NBUF * ASZ;
  const int t = threadIdx.x;
  const int lane = t & 63, w = t >> 6;
  const int g = lane >> 4, lr = lane & 15;
  const int wm = (w >> 1) * 64, wn = (w & 1) * (TN / 2);
  int m0, n0;
  if constexpr (SWZ) {
    const int gx = gridDim.x;
    const int lid = blockIdx.y * gx + blockIdx.x;
    const int chunk = (gx * gridDim.y) >> 3;
    const int sidx = (lid & 7) * chunk + (lid >> 3);
    m0 = (sidx / gx) * 128;
    n0 = (sidx % gx) * TN;
  } else {
    m0 = blockIdx.y * 128;
    n0 = blockIdx.x * TN;
  }
  const int nIter = K / BK;

  const int mac0 = t >> 3;
  const int v0 = ((t & 7) ^ (mac0 & 7)) << 4;
  const int rsw = (lr & 7) << 4;
  const int rdA = lr * 128 + (((wm & 64) + g * 16) ^ rsw);
  const int rdB = lr * 128 + ((((TN == 128) ? (wn & 64) : ((wn & 32) * 2)) + g * 16) ^ rsw);

  f32x4 acc[4][NI] = {};

  if constexpr (BK == 32) {
    const int cc0 = v0 & 63;
    const int growA = mac0 + ((v0 >> 6) << 6);
    const int growB = mac0 + ((v0 >> 6) << (TN == 128 ? 6 : 5));
    const char* srcA0 = (const char*)A + ((size_t)(m0 + growA) * K) * 2 + cc0;
    const char* srcA1 = srcA0 + (size_t)32 * K * 2;
    const char* srcB0 = (const char*)Bt + ((size_t)(n0 + growB) * K) * 2 + cc0;
    const char* srcB1 = srcB0 + (size_t)32 * K * 2;  // used only when TN==128

#define STAGE32(IT, BUF)                                                  \
  do {                                                                    \
    size_t kb = (size_t)(IT) * 64;                                        \
    gld16(srcA0 + kb, a_lds + (BUF) * ASZ + t * 16);                      \
    gld16(srcA1 + kb, a_lds + (BUF) * ASZ + 4096 + t * 16);               \
    gld16(srcB0 + kb, b_lds + (BUF) * BSZ + t * 16);                      \
    if constexpr (TN == 128)                                              \
      gld16(srcB1 + kb, b_lds + (BUF) * BSZ + 4096 + t * 16);             \
  } while (0)

#define GSTEP32(BUF)                                                         \
  do {                                                                       \
    bf16x8 af[4], bfr[NI];                                                   \
    _Pragma("unroll") for (int mi = 0; mi < 4; mi++)                         \
        af[mi] = *(const bf16x8*)(a_lds + (BUF) * ASZ + rdA + mi * 2048);    \
    _Pragma("unroll") for (int ni = 0; ni < NI; ni++)                        \
        bfr[ni] = *(const bf16x8*)(b_lds + (BUF) * BSZ + rdB + ni * 2048);   \
    _Pragma("unroll") for (int mi = 0; mi < 4; mi++)                         \
        _Pragma("unroll") for (int ni = 0; ni < NI; ni++)                    \
            acc[mi][ni] = mfma16(af[mi], bfr[ni], acc[mi][ni]);              \
  } while (0)

    if constexpr (NBUF == 2) {
      STAGE32(0, 0);
      int cur = 0;
#pragma unroll 1
      for (int it = 0; it < nIter; ++it) {
        WAITBAR0();
        if (it + 1 < nIter) STAGE32(it + 1, cur ^ 1);
        GSTEP32(cur);
        cur ^= 1;
      }
    } else {
      STAGE32(0, 0);
      STAGE32(1, 1);
      int b0 = 0, b1 = 1, b2 = 2;
#pragma unroll 1
      for (int it = 0; it < nIter - 1; ++it) {
        if constexpr (TN == 128) {
          asm volatile("s_waitcnt vmcnt(4)" ::: "memory");
        } else {
          asm volatile("s_waitcnt vmcnt(3)" ::: "memory");
        }
        __builtin_amdgcn_s_barrier();
        __builtin_amdgcn_sched_barrier(0);
        if (it + 2 < nIter) STAGE32(it + 2, b2);
        GSTEP32(b0);
        int tmp = b0; b0 = b1; b1 = b2; b2 = tmp;
      }
      WAITBAR0();
      GSTEP32(b0);
    }
#undef STAGE32
#undef GSTEP32
  } else {
    // ---- BK == 64 (TN == 64, NBUF == 2): rows are exact 128B macro-rows ----
    const char* sA0 = (const char*)A + ((size_t)(m0 + mac0) * K) * 2 + v0;
    const char* sA1 = sA0 + (size_t)32 * K * 2;
    const char* sA2 = sA0 + (size_t)64 * K * 2;
    const char* sA3 = sA0 + (size_t)96 * K * 2;
    const char* sB0 = (const char*)Bt + ((size_t)(n0 + mac0) * K) * 2 + v0;
    const char* sB1 = sB0 + (size_t)32 * K * 2;

#define STAGE64(IT, BUF)                                                  \
  do {                                                                    \
    size_t kb = (size_t)(IT) * 128;                                       \
    gld16(sA0 + kb, a_lds + (BUF) * ASZ + t * 16);                        \
    gld16(sA1 + kb, a_lds + (BUF) * ASZ + 4096 + t * 16);                 \
    gld16(sA2 + kb, a_lds + (BUF) * ASZ + 8192 + t * 16);                 \
    gld16(sA3 + kb, a_lds + (BUF) * ASZ + 12288 + t * 16);                \
    gld16(sB0 + kb, b_lds + (BUF) * BSZ + t * 16);                        \
    gld16(sB1 + kb, b_lds + (BUF) * BSZ + 4096 + t * 16);                 \
  } while (0)

#define GSTEP64(BUF)                                                           \
  do {                                                                         \
    _Pragma("unroll") for (int kk = 0; kk < 2; ++kk) {                         \
      bf16x8 af[4], bfr[2];                                                    \
      _Pragma("unroll") for (int mi = 0; mi < 4; mi++)                         \
          af[mi] = *(const bf16x8*)(a_lds + (BUF) * ASZ +                      \
                                    (wm + mi * 16 + lr) * 128 +                \
                                    ((kk * 64 + g * 16) ^ rsw));               \
      _Pragma("unroll") for (int ni = 0; ni < 2; ni++)                         \
          bfr[ni] = *(const bf16x8*)(b_lds + (BUF) * BSZ +                     \
                                     (wn + ni * 16 + lr) * 128 +               \
                                     ((kk * 64 + g * 16) ^ rsw));              \
      _Pragma("unroll") for (int mi = 0; mi < 4; mi++)                         \
          _Pragma("unroll") for (int ni = 0; ni < 2; ni++)                     \
              acc[mi][ni] = mfma16(af[mi], bfr[ni], acc[mi][ni]);              \
    }                                                                          \
  } while (0)

    STAGE64(0, 0);
    int cur = 0;
#pragma unroll 1
    for (int it = 0; it < nIter; ++it) {
      WAITBAR0();
      if (it + 1 < nIter) STAGE64(it + 1, cur ^ 1);
      GSTEP64(cur);
      cur ^= 1;
    }
#undef STAGE64
#undef GSTEP64
  }

  if (MODE == 0) {
    const int whichB = n0 >> 10;  // block-uniform (1024 % 128 == 0)
    if (whichB == 2) {
      // ---- V epilogue: LDS transpose + sigma permute, then coalesced 16B writes ----
      __syncthreads();  // all waves done reading pipeline LDS
#pragma unroll
      for (int mi = 0; mi < 4; mi++) {
        int colbase = wm + mi * 16 + g * 4;  // nn_local base (multiple of 4)
        int off = colbase & 63;
        int cpos = (off & 35) | ((off & 4) << 1) | ((off & 8) << 1) | ((off & 16) >> 2);
        int nplb = ((colbase & 64) + cpos) * 2;  // byte base within 256B row
#pragma unroll
        for (int ni = 0; ni < NI; ni++) {
          int rl = wn + ni * 16 + lr;  // dd_local row
          float bia = bias[n0 + rl];
          unsigned short v4[4];
#pragma unroll
          for (int j = 0; j < 4; j++) v4[j] = f2bf(acc[mi][ni][j] + bia);
          int byt = rl * 256 + (nplb ^ ((rl & 7) << 4));
          *(unsigned long long*)(lds_all + byt) = *(const unsigned long long*)v4;
        }
      }
      __syncthreads();
      int r = t >> 1, half = t & 1;
      int hh = ((n0 & 1023) >> 6) + (r >> 6);
      int dd = r & 63;
      int bb = m0 >> 11;
      char* dst = (char*)outp +
                  2 * ((size_t)2 * TOK * D_ +
                       ((size_t)(bb * NH + hh) * HD + dd) * SEQ + (m0 & 2047) + half * 64);
#pragma unroll
      for (int c = 0; c < 8; c++) {
        int src = r * 256 + ((half * 128 + c * 16) ^ ((r & 7) << 4));
        *(int4*)(dst + c * 16) = *(const int4*)(lds_all + src);
      }
    } else {
      // ---- q/k epilogue: direct stores (32B-coalesced per quarter-wave) ----
#pragma unroll
      for (int mi = 0; mi < 4; mi++) {
#pragma unroll
        for (int ni = 0; ni < NI; ni++) {
#pragma unroll
          for (int j = 0; j < 4; j++) {
            int row = m0 + wm + mi * 16 + g * 4 + j;
            int col = n0 + wn + ni * 16 + lr;
            float val = acc[mi][ni][j] + bias[col];
            int cc = col & 1023;
            int hh = cc >> 6, dd = cc & 63;
            int bb = row >> 11, nn = row & 2047;
            if (whichB == 0) val *= 0.18033688011112042f;  // 0.125 * log2(e)
            ((unsigned short*)outp)[(size_t)whichB * (TOK * D_) +
                                    (((size_t)(bb * NH + hh) * SEQ + nn) << 6) + dd] =
                f2bf(val);
          }
        }
      }
    }
    return;
  }

#pragma unroll
  for (int mi = 0; mi < 4; mi++) {
#pragma unroll
    for (int ni = 0; ni < NI; ni++) {
#pragma unroll
      for (int j = 0; j < 4; j++) {
        int row = m0 + wm + mi * 16 + g * 4 + j;
        int col = n0 + wn + ni * 16 + lr;
        float val = acc[mi][ni][j];
        if (MODE == 2) {
          val += bias[col];
          val = 0.5f * val * (1.0f + erff(val * 0.70710678118f));
          ((unsigned short*)outp)[(size_t)row * N + col] = f2bf(val);
        } else if (MODE == 5) {
          val += bias[col] + resid[(size_t)row * N + col];
          ((float*)outp)[(size_t)row * N + col] = val;
        }
      }
    }
  }
}

// ---------------- Flash attention v10 (r12 body, proven 62us): no max tracking ----------------
// q (pre-scaled by 0.125*log2e), k: [B][H][N][64]; vT: [B][H][64][N] (sigma-permuted).
// 1024 blocks x 4 waves; 64 q-rows/block (16/wave); KVBLK=64 2-buffer.
__global__ __launch_bounds__(256, 4) void attn_kernel(const unsigned short* __restrict__ q,
                                                      const unsigned short* __restrict__ k,
                                                      const unsigned short* __restrict__ vT,
                                                      unsigned short* __restrict__ ao) {
  // LDS arena: K buf0 @0, K buf1 @8192, V buf0 @16384, V buf1 @24576
  __shared__ __align__(16) char ldsb[32768];
  const int t = threadIdx.x, lane = t & 63, w = t >> 6;
  const int g = lane >> 4, lr = lane & 15;
  const int bid = (blockIdx.x & 7) * 128 + (blockIdx.x >> 3);  // XCD swizzle
  const int qt = bid & 31, bh = bid >> 5;
  const int bb = bh >> 4, hh = bh & 15;

  const unsigned short* qp = q + ((size_t)bh * SEQ + qt * 64 + w * 16) * HD;
  bf16x8 qf0 = *(const bf16x8*)(qp + lr * HD + g * 8);
  bf16x8 qf1 = *(const bf16x8*)(qp + lr * HD + 32 + g * 8);

  f32x4 oacc[4] = {};
  f32x4 spv = {0.f, 0.f, 0.f, 0.f};  // 4 parallel denominator chains

  const int srow = t >> 3, sc = (t & 7) << 4;
  const int ssw = sc ^ ((srow & 7) << 4);
  const char* kgl = (const char*)(k + (size_t)bh * SEQ * HD) + srow * 128 + ssw;
  const char* vgl = (const char*)(vT + (size_t)bh * HD * SEQ) + (size_t)srow * 4096 + ssw;
  char* kdst = ldsb + w * 1024;            // + buf*8192 (+4096 for rows 32-63)
  char* vdst = ldsb + 16384 + w * 1024;    // + buf*8192

  const int rsw = (lr & 7) << 4;
  const char* r0 = ldsb + lr * 128 + ((g * 16) ^ rsw);
  const char* r1 = ldsb + lr * 128 + ((64 + g * 16) ^ rsw);

#define ISSUE(BUF)                                   \
  do {                                               \
    gld16(kgl, kdst + (BUF) * 8192);                 \
    gld16(kgl + 4096, kdst + (BUF) * 8192 + 4096);   \
    gld16(vgl, vdst + (BUF) * 8192);                 \
    gld16(vgl + 131072, vdst + (BUF) * 8192 + 4096); \
    kgl += 8192;                                     \
    vgl += 128;                                      \
  } while (0)

#define COMPUTE(BUF)                                                                     \
  do {                                                                                   \
    f32x4 sT[4];                                                                         \
    __builtin_amdgcn_s_setprio(1);                                                       \
    _Pragma("unroll") for (int sb = 0; sb < 4; ++sb) {                                   \
      bf16x8 kf0 = *(const bf16x8*)(r0 + (BUF) * 8192 + sb * 2048);                      \
      bf16x8 kf1 = *(const bf16x8*)(r1 + (BUF) * 8192 + sb * 2048);                      \
      f32x4 zz = {};                                                                     \
      zz = mfma16(kf0, qf0, zz);                                                         \
      sT[sb] = mfma16(kf1, qf1, zz);                                                     \
    }                                                                                    \
    __builtin_amdgcn_s_setprio(0);                                                       \
    float p[4][4];                                                                       \
    _Pragma("unroll") for (int sb = 0; sb < 4; ++sb) _Pragma("unroll")                   \
        for (int jr = 0; jr < 4; ++jr) {                                                 \
      p[sb][jr] = exp2f(sT[sb][jr]);                                                     \
      spv[jr] += p[sb][jr];                                                              \
    }                                                                                    \
    u32x4 pA[2];                                                                         \
    _Pragma("unroll") for (int kk = 0; kk < 2; ++kk) pA[kk] =                            \
        (u32x4){cvtpk(p[2 * kk][0], p[2 * kk][1]), cvtpk(p[2 * kk][2], p[2 * kk][3]),    \
                cvtpk(p[2 * kk + 1][0], p[2 * kk + 1][1]),                               \
                cvtpk(p[2 * kk + 1][2], p[2 * kk + 1][3])};                              \
    __builtin_amdgcn_s_setprio(1);                                                       \
    _Pragma("unroll") for (int vb = 0; vb < 4; ++vb) {                                   \
      bf16x8 v0 = *(const bf16x8*)(r0 + 16384 + (BUF) * 8192 + vb * 2048);               \
      bf16x8 v1 = *(const bf16x8*)(r1 + 16384 + (BUF) * 8192 + vb * 2048);               \
      oacc[vb] = mfma16(__builtin_bit_cast(bf16x8, pA[0]), v0, oacc[vb]);                \
      oacc[vb] = mfma16(__builtin_bit_cast(bf16x8, pA[1]), v1, oacc[vb]);                \
    }                                                                                    \
    __builtin_amdgcn_s_setprio(0);                                                       \
  } while (0)

  ISSUE(0);  // prolog: tile 0 loads in flight

  int staged = 1;
#pragma unroll 1
  for (int i2 = 0; i2 < SEQ / 128; ++i2) {
    WAITBAR0();
    if (staged < SEQ / 64) { ISSUE(1); ++staged; }
    COMPUTE(0);
    WAITBAR0();
    if (staged < SEQ / 64) { ISSUE(0); ++staged; }
    COMPUTE(1);
  }
#undef ISSUE
#undef COMPUTE

  float sp = (spv[0] + spv[1]) + (spv[2] + spv[3]);
  sp += __shfl_xor(sp, 16);
  sp += __shfl_xor(sp, 32);

#pragma unroll
  for (int jj = 0; jj < 4; ++jj) {
    float li = 1.0f / __shfl(sp, g * 4 + jj);
    int nrow = qt * 64 + w * 16 + g * 4 + jj;
#pragma unroll
    for (int vb = 0; vb < 4; ++vb)
      ao[((size_t)bb * SEQ + nrow) * D_ + hh * HD + vb * 16 + lr] = f2bf(oacc[vb][jj] * li);
  }
}

extern "C" void kernel_launch(void* const* d_in, const int* in_sizes, int n_in,
                              void* d_out, int out_size, void* d_ws, size_t ws_size,
                              hipStream_t stream) {
  const float* x     = (const float*)d_in[0];
  const float* w_qkv = (const float*)d_in[1];
  const float* b_qkv = (const float*)d_in[2];
  const float* w_out = (const float*)d_in[3];
  const float* b_out = (const float*)d_in[4];
  const float* w_fc1 = (const float*)d_in[5];
  const float* b_fc1 = (const float*)d_in[6];
  const float* w_fc2 = (const float*)d_in[7];
  const float* b_fc2 = (const float*)d_in[8];
  const float* ln1_g = (const float*)d_in[9];
  const float* ln1_b = (const float*)d_in[10];
  const float* ln2_g = (const float*)d_in[11];
  const float* ln2_b = (const float*)d_in[12];
  float* out = (float*)d_out;

  char* ws = (char*)d_ws;
  unsigned short* wqkvT = (unsigned short*)(ws);              //  6 MB [3072][1024]
  unsigned short* woutT = (unsigned short*)(ws + 6291456);    //  2 MB [1024][1024]
  unsigned short* wfc1T = (unsigned short*)(ws + 8388608);    //  8 MB [4096][1024]
  unsigned short* wfc2T = (unsigned short*)(ws + 16777216);   //  8 MB [1024][4096]
  unsigned short* h     = (unsigned short*)(ws + 25165824);   //  8 MB [4096][1024]
  unsigned short* qkv   = (unsigned short*)(ws + 33554432);   // 24 MB q,k,vT
  unsigned short* ao    = (unsigned short*)(ws + 58720256);   //  8 MB [4096][1024]
  float*          x1    = (float*)(ws + 67108864);            // 16 MB [4096][1024]
  unsigned short* hg    = (unsigned short*)(ws + 83886080);   // 32 MB [4096][4096]

  prep_kernel<<<13312, 256, 0, stream>>>(w_qkv, w_out, w_fc1, w_fc2,
                                         wqkvT, woutT, wfc1T, wfc2T,
                                         x, ln1_g, ln1_b, h);
  gemm_bt<0, 3, 128, 0, 32><<<dim3(24, 32), 256, 0, stream>>>(h, wqkvT, b_qkv, nullptr, qkv,
                                                              TOK, 3072, 1024);
  attn_kernel<<<1024, 256, 0, stream>>>(qkv, qkv + (size_t)TOK * D_, qkv + 2 * (size_t)TOK * D_,
                                        ao);
  gemm_bt<5, 2, 64, 0, 64><<<dim3(16, 32), 256, 0, stream>>>(ao, woutT, b_out, x, x1,
                                                             TOK, 1024, 1024);
  layernorm_bf16<<<TOK / 4, 256, 0, stream>>>(x1, ln2_g, ln2_b, h);
  gemm_bt<2, 2, 128, 0, 32><<<dim3(32, 32), 256, 0, stream>>>(h, wfc1T, b_fc1, nullptr, hg,
                                                              TOK, 4096, 1024);
  gemm_bt<5, 2, 64, 1, 64><<<dim3(16, 32), 256, 0, stream>>>(hg, wfc2T, b_fc2, x1, out,
                                                             TOK, 1024, 4096);
}